// Round 4
// baseline (443.866 us; speedup 1.0000x reference)
//
#include <hip/hip_runtime.h>
#include <hip/hip_bf16.h>
#include <math.h>
#include <stdint.h>
#include <string.h>

#define BB 8
#define SS 96
#define DD 768
#define RR 24
#define RSEQ 8
#define TAG 3
#define D3 2304   // 3*D
#define NC 72     // R*TAG

typedef __attribute__((ext_vector_type(8))) short bf16x8;
typedef __attribute__((ext_vector_type(4))) float f32x4;

// round-half-up f32 pair -> packed bf16x2 (values are relu'd: >=0, no NaN)
static __device__ inline uint32_t pkrhu(float lo, float hi) {
  uint32_t a, b;
  memcpy(&a, &lo, 4);
  memcpy(&b, &hi, 4);
  return ((a + 0x8000u) >> 16) | ((b + 0x8000u) & 0xFFFF0000u);
}
// RNE f32 -> bf16
static __device__ inline uint16_t bf16c(float v) {
  uint32_t u;
  memcpy(&u, &v, 4);
  u += 0x7FFFu + ((u >> 16) & 1u);
  return (uint16_t)(u >> 16);
}
static __device__ inline uint32_t pkrne(float lo, float hi) {
  uint32_t a, b;
  memcpy(&a, &lo, 4);
  memcpy(&b, &hi, 4);
  a += 0x7FFFu + ((a >> 16) & 1u);
  b += 0x7FFFu + ((b >> 16) & 1u);
  return (a >> 16) | (b & 0xFFFF0000u);
}
static __device__ inline float lo16f(uint32_t u) {
  const uint32_t v = u << 16;
  float f;
  memcpy(&f, &v, 4);
  return f;
}
static __device__ inline float hi16f(uint32_t u) {
  const uint32_t v = u & 0xFFFF0000u;
  float f;
  memcpy(&f, &v, 4);
  return f;
}

// ---------------------------------------------------------------------------
// Kernel P0: Wb[96][2304] bf16 = rel_W^T (rows 72..95 zero).
// ---------------------------------------------------------------------------
__global__ __launch_bounds__(256) void k_prepW(const float* __restrict__ relW,
                                               uint16_t* __restrict__ Wb) {
  const int e = blockIdx.x * 256 + threadIdx.x;  // 96*2304
  const int n = e / D3, k = e % D3;
  float v = (n < NC) ? relW[(size_t)k * NC + n] : 0.f;
  Wb[e] = bf16c(v);
}

// ---------------------------------------------------------------------------
// Kernel P1: T[2304][1536] bf16 = proj_W^T, 64x64 LDS-tiled transpose.
// ---------------------------------------------------------------------------
__global__ __launch_bounds__(256) void k_trans(const float* __restrict__ W,
                                               uint16_t* __restrict__ T) {
  __shared__ float tile[64][65];
  const int c0 = blockIdx.x * 64;
  const int r0 = blockIdx.y * 64;
  const int t = threadIdx.x;
  {
    const int tr = t >> 4;
    const int tc4 = (t & 15) * 4;
#pragma unroll
    for (int p = 0; p < 4; ++p) {
      const int r = tr + p * 16;
      const float4 v = *(const float4*)&W[(size_t)(r0 + r) * D3 + c0 + tc4];
      tile[r][tc4 + 0] = v.x;
      tile[r][tc4 + 1] = v.y;
      tile[r][tc4 + 2] = v.z;
      tile[r][tc4 + 3] = v.w;
    }
  }
  __syncthreads();
  {
    const int cc = t >> 4;
    const int rr4 = (t & 15) * 4;
#pragma unroll
    for (int p = 0; p < 4; ++p) {
      const int c = cc + p * 16;
      uint2 w;
      w.x = pkrne(tile[rr4 + 0][c], tile[rr4 + 1][c]);
      w.y = pkrne(tile[rr4 + 2][c], tile[rr4 + 3][c]);
      *(uint2*)&T[(size_t)(c0 + c) * (2 * DD) + r0 + rr4] = w;
    }
  }
}

// ---------------------------------------------------------------------------
// Kernel 1: refine (algebraic collapse of 24 sequential attention steps).
// Output: enc' bf16 [768][768] k-contiguous.
// ---------------------------------------------------------------------------
__global__ __launch_bounds__(256) void k_refine(const float* __restrict__ enc,
                                                const float* __restrict__ rel,
                                                uint16_t* __restrict__ encRb) {
  const int b = blockIdx.x;
  const int t = threadIdx.x;
  __shared__ float As[RSEQ][DD + 4];
  __shared__ float S0[RSEQ][SS];
  __shared__ float G[RSEQ][RSEQ];
  __shared__ float P[RSEQ][SS];
  __shared__ float sc[RSEQ][SS];
  const float scale = 0.036084391824351613f;  // 1/sqrt(768)

  const float* Ag = rel + (size_t)b * RSEQ * DD;
  for (int e = t; e < RSEQ * DD; e += 256) As[e / DD][e % DD] = Ag[e];
  for (int e = t; e < RSEQ * SS; e += 256) ((float*)P)[e] = 0.f;
  __syncthreads();

  if (t < 64) {
    const int r0 = t >> 3, r1 = t & 7;
    float a0 = 0.f, a1 = 0.f, a2 = 0.f, a3 = 0.f;
    for (int d = 0; d < DD; d += 4) {
      a0 += As[r0][d + 0] * As[r1][d + 0];
      a1 += As[r0][d + 1] * As[r1][d + 1];
      a2 += As[r0][d + 2] * As[r1][d + 2];
      a3 += As[r0][d + 3] * As[r1][d + 3];
    }
    G[r0][r1] = a0 + a1 + a2 + a3;
  }
  const float* Eb = enc + (size_t)b * SS * DD;
  for (int e = t; e < RSEQ * SS; e += 256) {
    const int r = e & 7, s = e >> 3;
    const float* row = Eb + (size_t)s * DD;
    float a0 = 0.f, a1 = 0.f, a2 = 0.f, a3 = 0.f;
    for (int d = 0; d < DD; d += 4) {
      const float4 rv = *(const float4*)&row[d];
      a0 += As[r][d + 0] * rv.x;
      a1 += As[r][d + 1] * rv.y;
      a2 += As[r][d + 2] * rv.z;
      a3 += As[r][d + 3] * rv.w;
    }
    S0[r][s] = a0 + a1 + a2 + a3;
  }
  __syncthreads();

  const int wave = t >> 6, lane = t & 63;
  for (int step = 0; step < RR; ++step) {
    for (int e = t; e < RSEQ * SS; e += 256) {
      const int r = e / SS, s = e % SS;
      float acc = S0[r][s];
#pragma unroll
      for (int r2 = 0; r2 < RSEQ; ++r2) acc += G[r][r2] * P[r2][s];
      sc[r][s] = acc * scale;
    }
    __syncthreads();
#pragma unroll
    for (int rr = 0; rr < 2; ++rr) {
      const int r = wave * 2 + rr;
      const float m1 = sc[r][lane];
      const float m2 = (lane < 32) ? sc[r][lane + 64] : -1e30f;
      float mx = fmaxf(m1, m2);
#pragma unroll
      for (int o = 32; o > 0; o >>= 1) mx = fmaxf(mx, __shfl_xor(mx, o, 64));
      const float e1 = __expf(m1 - mx);
      const float e2 = (lane < 32) ? __expf(m2 - mx) : 0.f;
      float sm = e1 + e2;
#pragma unroll
      for (int o = 32; o > 0; o >>= 1) sm += __shfl_xor(sm, o, 64);
      const float inv = 1.f / sm;
      P[r][lane] += e1 * inv;
      if (lane < 32) P[r][lane + 64] += e2 * inv;
    }
    __syncthreads();
  }

  uint16_t* Ob = encRb + (size_t)b * SS * DD;
  for (int e = t; e < SS * DD / 4; e += 256) {
    const int s = (e * 4) / DD;
    const int d = (e * 4) % DD;
    float4 v = ((const float4*)Eb)[e];
#pragma unroll
    for (int r = 0; r < RSEQ; ++r) {
      const float p = P[r][s];
      v.x += p * As[r][d + 0];
      v.y += p * As[r][d + 1];
      v.z += p * As[r][d + 2];
      v.w += p * As[r][d + 3];
    }
    uint2 w;
    w.x = pkrhu(v.x, v.y);
    w.y = pkrhu(v.z, v.w);
    *(uint2*)&Ob[e * 4] = w;
  }
}

// ---------------------------------------------------------------------------
// Kernel 2: projection GEMM, bf16 MFMA, no LDS, barrier-free.
// Block tile 64m x 64n, 4 waves (wave = m-tile), per wave 1 A + 4 B frags +
// 4 MFMA per 32-k chunk, 1-deep prefetch. grid (12, 72).
// Outputs: Hh f32 (bias folded), Ht bf16 (halves k_pairs' L2 stream).
// ---------------------------------------------------------------------------
__global__ __launch_bounds__(256) void k_proj(const uint16_t* __restrict__ Ab,
                                              const uint16_t* __restrict__ Bt,
                                              const float* __restrict__ pb,
                                              float* __restrict__ Hh,
                                              uint16_t* __restrict__ Htb) {
  const int m0 = blockIdx.x * 64;
  const int gn0 = blockIdx.y * 64;
  const bool isH = gn0 < D3;               // uniform per block
  const int n0 = isH ? gn0 : gn0 - D3;
  const int halfk = isH ? 0 : DD;
  const int t = threadIdx.x, w = t >> 6, lane = t & 63;
  const int lm = lane & 15, q = lane >> 4, kq = q * 8;

  const uint16_t* arow = Ab + (size_t)(m0 + w * 16 + lm) * DD + kq;
  const uint16_t* brow[4];
#pragma unroll
  for (int nt = 0; nt < 4; ++nt)
    brow[nt] = Bt + (size_t)(n0 + nt * 16 + lm) * (2 * DD) + halfk + kq;

  f32x4 acc[4];
#pragma unroll
  for (int nt = 0; nt < 4; ++nt) acc[nt] = (f32x4){0.f, 0.f, 0.f, 0.f};

  bf16x8 ac = *(const bf16x8*)arow;
  bf16x8 bc[4];
#pragma unroll
  for (int nt = 0; nt < 4; ++nt) bc[nt] = *(const bf16x8*)brow[nt];

  for (int k0 = 0; k0 < DD; k0 += 32) {
    const int kn = (k0 + 32 < DD) ? k0 + 32 : 0;  // last-iter: harmless reload
    const bf16x8 an = *(const bf16x8*)(arow + kn);
    bf16x8 bn[4];
#pragma unroll
    for (int nt = 0; nt < 4; ++nt) bn[nt] = *(const bf16x8*)(brow[nt] + kn);
#pragma unroll
    for (int nt = 0; nt < 4; ++nt)
      acc[nt] = __builtin_amdgcn_mfma_f32_16x16x32_bf16(ac, bc[nt], acc[nt], 0, 0, 0);
    ac = an;
#pragma unroll
    for (int nt = 0; nt < 4; ++nt) bc[nt] = bn[nt];
  }

  // epilogue: C layout col=lm, row=q*4+r
#pragma unroll
  for (int nt = 0; nt < 4; ++nt) {
    const int ncol = n0 + nt * 16 + lm;
    if (isH) {
      const float bias = pb[ncol];
#pragma unroll
      for (int r = 0; r < 4; ++r)
        Hh[(size_t)(m0 + w * 16 + q * 4 + r) * D3 + ncol] = acc[nt][r] + bias;
    } else {
#pragma unroll
      for (int r = 0; r < 4; ++r)
        Htb[(size_t)(m0 + w * 16 + q * 4 + r) * D3 + ncol] = bf16c(acc[nt][r]);
    }
  }
}

// ---------------------------------------------------------------------------
// Kernel 3: pairwise GEMM, barrier-free (no K-loop __syncthreads).
// Block (b,i): 6 waves, wave w owns j-tile [16w,16w+16) x all 5 N-tiles.
// Per 32-k chunk per lane: 1 bf16x8 Ht load (prefetched) + 2 broadcast
// ds_reads of Hrow + in-register relu+pack A-frag + 5 Wb loads + 5 MFMA.
// A built exactly once chip-wide; latency hidden by occupancy (no barriers).
// ---------------------------------------------------------------------------
__global__ __launch_bounds__(384, 5) void k_pairs(const float* __restrict__ Hh,
                                                  const uint16_t* __restrict__ Htb,
                                                  const uint16_t* __restrict__ Wb,
                                                  const float* __restrict__ relb,
                                                  float* __restrict__ out) {
  const int bi = blockIdx.x;
  const int b = bi / SS, i = bi % SS;
  const int t = threadIdx.x;
  const int w = t >> 6, lane = t & 63;
  const int lm = lane & 15, q = lane >> 4;

  __shared__ float Hrow[D3];  // 9.2 KB

  const float* hh = Hh + (size_t)bi * D3;
  for (int e = t; e < D3 / 4; e += 384) ((float4*)Hrow)[e] = ((const float4*)hh)[e];
  __syncthreads();  // the only block-wide barrier

  const uint16_t* htrow = Htb + ((size_t)b * SS + w * 16 + lm) * D3 + q * 8;
  const uint16_t* wb0 = Wb + (size_t)(0 * 16 + lm) * D3 + q * 8;
  const uint16_t* wb1 = Wb + (size_t)(1 * 16 + lm) * D3 + q * 8;
  const uint16_t* wb2 = Wb + (size_t)(2 * 16 + lm) * D3 + q * 8;
  const uint16_t* wb3 = Wb + (size_t)(3 * 16 + lm) * D3 + q * 8;
  const uint16_t* wb4 = Wb + (size_t)(4 * 16 + lm) * D3 + q * 8;

  f32x4 acc[5];
#pragma unroll
  for (int nt = 0; nt < 5; ++nt) acc[nt] = (f32x4){0.f, 0.f, 0.f, 0.f};

  uint4 htc = *(const uint4*)htrow;  // current chunk's 8 bf16 of Ht row

  for (int k0 = 0; k0 < D3; k0 += 32) {
    const int kn = (k0 + 32 < D3) ? k0 + 32 : 0;  // last-iter: harmless reload
    const uint4 htn = *(const uint4*)(htrow + kn);
    bf16x8 bfr[5];
    bfr[0] = *(const bf16x8*)(wb0 + k0);
    bfr[1] = *(const bf16x8*)(wb1 + k0);
    bfr[2] = *(const bf16x8*)(wb2 + k0);
    bfr[3] = *(const bf16x8*)(wb3 + k0);
    bfr[4] = *(const bf16x8*)(wb4 + k0);
    const float4 hr0 = *(const float4*)&Hrow[k0 + q * 8];      // LDS broadcast
    const float4 hr1 = *(const float4*)&Hrow[k0 + q * 8 + 4];

    // A-frag: relu(Hrow + bf16(Ht)) -> bf16, 8 consecutive k
    union { bf16x8 v; uint32_t u[4]; } pk;
    pk.u[0] = pkrhu(fmaxf(lo16f(htc.x) + hr0.x, 0.f), fmaxf(hi16f(htc.x) + hr0.y, 0.f));
    pk.u[1] = pkrhu(fmaxf(lo16f(htc.y) + hr0.z, 0.f), fmaxf(hi16f(htc.y) + hr0.w, 0.f));
    pk.u[2] = pkrhu(fmaxf(lo16f(htc.z) + hr1.x, 0.f), fmaxf(hi16f(htc.z) + hr1.y, 0.f));
    pk.u[3] = pkrhu(fmaxf(lo16f(htc.w) + hr1.z, 0.f), fmaxf(hi16f(htc.w) + hr1.w, 0.f));

#pragma unroll
    for (int nt = 0; nt < 5; ++nt)
      acc[nt] = __builtin_amdgcn_mfma_f32_16x16x32_bf16(pk.v, bfr[nt], acc[nt], 0, 0, 0);
    htc = htn;
  }

  // epilogue: C layout col=lm (c), row=q*4+r (j-within-tile)
#pragma unroll
  for (int nt = 0; nt < 5; ++nt) {
    const int c = nt * 16 + lm;
    if (c < NC) {
      const float rb = relb[c];
      const int r = c / 3, tg = c % 3;
      float* base = out + ((((size_t)b * TAG + tg) * RR + r) * SS + i) * SS + w * 16 + q * 4;
      float4 o;
      o.x = acc[nt][0] + rb;
      o.y = acc[nt][1] + rb;
      o.z = acc[nt][2] + rb;
      o.w = acc[nt][3] + rb;
      *(float4*)base = o;
    }
  }
}

// ---------------------------------------------------------------------------
extern "C" void kernel_launch(void* const* d_in, const int* in_sizes, int n_in,
                              void* d_out, int out_size, void* d_ws, size_t ws_size,
                              hipStream_t stream) {
  const float* enc   = (const float*)d_in[0];  // [8,96,768]
  const float* rel   = (const float*)d_in[1];  // [24,8,768]
  const float* projW = (const float*)d_in[2];  // [1536,2304]
  const float* projb = (const float*)d_in[3];  // [2304]
  const float* relW  = (const float*)d_in[4];  // [2304,72]
  const float* relb  = (const float*)d_in[5];  // [72]
  float* out = (float*)d_out;                  // [8,3,24,96,96]

  float* Hh = (float*)d_ws;                               // 768*2304 f32
  uint16_t* Htb = (uint16_t*)(Hh + (size_t)DD * D3);      // 768*2304 bf16
  uint16_t* Wb = Htb + (size_t)DD * D3;                   // 96*2304 bf16
  uint16_t* Tp = Wb + (size_t)96 * D3;                    // 2304*1536 bf16
  uint16_t* Ab = Tp + (size_t)D3 * 2 * DD;                // 768*768 bf16

  k_prepW<<<(96 * D3) / 256, 256, 0, stream>>>(relW, Wb);
  k_trans<<<dim3(36, 24), 256, 0, stream>>>(projW, Tp);
  k_refine<<<BB, 256, 0, stream>>>(enc, rel, Ab);
  k_proj<<<dim3(12, 72), 256, 0, stream>>>(Ab, Tp, projb, Hh, Htb);
  k_pairs<<<BB * SS, 384, 0, stream>>>(Hh, Htb, Wb, relb, out);
}

// Round 5
// 260.149 us; speedup vs baseline: 1.7062x; 1.7062x over previous
//
#include <hip/hip_runtime.h>
#include <hip/hip_bf16.h>
#include <math.h>
#include <stdint.h>
#include <string.h>

#define BB 8
#define SS 96
#define DD 768
#define RR 24
#define RSEQ 8
#define TAG 3
#define D3 2304   // 3*D
#define NC 72     // R*TAG

typedef __attribute__((ext_vector_type(8))) short bf16x8;
typedef __attribute__((ext_vector_type(4))) float f32x4;

// round-half-up f32 pair -> packed bf16x2: add,add,v_perm = 3 VALU.
// (inputs are relu'd / well-scaled: no NaN/overflow concerns at lsb+0x8000)
static __device__ inline uint32_t pkrhu(float lo, float hi) {
  uint32_t a, b;
  memcpy(&a, &lo, 4);
  memcpy(&b, &hi, 4);
  return __builtin_amdgcn_perm(b + 0x8000u, a + 0x8000u, 0x07060302u);
}
// RNE f32 -> bf16 (cold paths)
static __device__ inline uint16_t bf16c(float v) {
  uint32_t u;
  memcpy(&u, &v, 4);
  u += 0x7FFFu + ((u >> 16) & 1u);
  return (uint16_t)(u >> 16);
}
static __device__ inline uint32_t pkrne(float lo, float hi) {
  uint32_t a, b;
  memcpy(&a, &lo, 4);
  memcpy(&b, &hi, 4);
  a += 0x7FFFu + ((a >> 16) & 1u);
  b += 0x7FFFu + ((b >> 16) & 1u);
  return (a >> 16) | (b & 0xFFFF0000u);
}
static __device__ inline float lo16f(uint32_t u) {
  const uint32_t v = u << 16;
  float f;
  memcpy(&f, &v, 4);
  return f;
}
static __device__ inline float hi16f(uint32_t u) {
  const uint32_t v = u & 0xFFFF0000u;
  float f;
  memcpy(&f, &v, 4);
  return f;
}

// ---------------------------------------------------------------------------
// Kernel P0: Wb[96][2304] bf16 = rel_W^T (rows 72..95 zero).
// ---------------------------------------------------------------------------
__global__ __launch_bounds__(256) void k_prepW(const float* __restrict__ relW,
                                               uint16_t* __restrict__ Wb) {
  const int e = blockIdx.x * 256 + threadIdx.x;  // 96*2304
  const int n = e / D3, k = e % D3;
  float v = (n < NC) ? relW[(size_t)k * NC + n] : 0.f;
  Wb[e] = bf16c(v);
}

// ---------------------------------------------------------------------------
// Kernel P1: T[2304][1536] bf16 = proj_W^T, 64x64 LDS-tiled transpose.
// ---------------------------------------------------------------------------
__global__ __launch_bounds__(256) void k_trans(const float* __restrict__ W,
                                               uint16_t* __restrict__ T) {
  __shared__ float tile[64][65];
  const int c0 = blockIdx.x * 64;
  const int r0 = blockIdx.y * 64;
  const int t = threadIdx.x;
  {
    const int tr = t >> 4;
    const int tc4 = (t & 15) * 4;
#pragma unroll
    for (int p = 0; p < 4; ++p) {
      const int r = tr + p * 16;
      const float4 v = *(const float4*)&W[(size_t)(r0 + r) * D3 + c0 + tc4];
      tile[r][tc4 + 0] = v.x;
      tile[r][tc4 + 1] = v.y;
      tile[r][tc4 + 2] = v.z;
      tile[r][tc4 + 3] = v.w;
    }
  }
  __syncthreads();
  {
    const int cc = t >> 4;
    const int rr4 = (t & 15) * 4;
#pragma unroll
    for (int p = 0; p < 4; ++p) {
      const int c = cc + p * 16;
      uint2 w;
      w.x = pkrne(tile[rr4 + 0][c], tile[rr4 + 1][c]);
      w.y = pkrne(tile[rr4 + 2][c], tile[rr4 + 3][c]);
      *(uint2*)&T[(size_t)(c0 + c) * (2 * DD) + r0 + rr4] = w;
    }
  }
}

// ---------------------------------------------------------------------------
// Kernel 1: refine (algebraic collapse of 24 sequential attention steps).
// Output: enc' bf16 [768][768] k-contiguous.
// ---------------------------------------------------------------------------
__global__ __launch_bounds__(256) void k_refine(const float* __restrict__ enc,
                                                const float* __restrict__ rel,
                                                uint16_t* __restrict__ encRb) {
  const int b = blockIdx.x;
  const int t = threadIdx.x;
  __shared__ float As[RSEQ][DD + 4];
  __shared__ float S0[RSEQ][SS];
  __shared__ float G[RSEQ][RSEQ];
  __shared__ float P[RSEQ][SS];
  __shared__ float sc[RSEQ][SS];
  const float scale = 0.036084391824351613f;  // 1/sqrt(768)

  const float* Ag = rel + (size_t)b * RSEQ * DD;
  for (int e = t; e < RSEQ * DD; e += 256) As[e / DD][e % DD] = Ag[e];
  for (int e = t; e < RSEQ * SS; e += 256) ((float*)P)[e] = 0.f;
  __syncthreads();

  if (t < 64) {
    const int r0 = t >> 3, r1 = t & 7;
    float a0 = 0.f, a1 = 0.f, a2 = 0.f, a3 = 0.f;
    for (int d = 0; d < DD; d += 4) {
      a0 += As[r0][d + 0] * As[r1][d + 0];
      a1 += As[r0][d + 1] * As[r1][d + 1];
      a2 += As[r0][d + 2] * As[r1][d + 2];
      a3 += As[r0][d + 3] * As[r1][d + 3];
    }
    G[r0][r1] = a0 + a1 + a2 + a3;
  }
  const float* Eb = enc + (size_t)b * SS * DD;
  for (int e = t; e < RSEQ * SS; e += 256) {
    const int r = e & 7, s = e >> 3;
    const float* row = Eb + (size_t)s * DD;
    float a0 = 0.f, a1 = 0.f, a2 = 0.f, a3 = 0.f;
    for (int d = 0; d < DD; d += 4) {
      const float4 rv = *(const float4*)&row[d];
      a0 += As[r][d + 0] * rv.x;
      a1 += As[r][d + 1] * rv.y;
      a2 += As[r][d + 2] * rv.z;
      a3 += As[r][d + 3] * rv.w;
    }
    S0[r][s] = a0 + a1 + a2 + a3;
  }
  __syncthreads();

  const int wave = t >> 6, lane = t & 63;
  for (int step = 0; step < RR; ++step) {
    for (int e = t; e < RSEQ * SS; e += 256) {
      const int r = e / SS, s = e % SS;
      float acc = S0[r][s];
#pragma unroll
      for (int r2 = 0; r2 < RSEQ; ++r2) acc += G[r][r2] * P[r2][s];
      sc[r][s] = acc * scale;
    }
    __syncthreads();
#pragma unroll
    for (int rr = 0; rr < 2; ++rr) {
      const int r = wave * 2 + rr;
      const float m1 = sc[r][lane];
      const float m2 = (lane < 32) ? sc[r][lane + 64] : -1e30f;
      float mx = fmaxf(m1, m2);
#pragma unroll
      for (int o = 32; o > 0; o >>= 1) mx = fmaxf(mx, __shfl_xor(mx, o, 64));
      const float e1 = __expf(m1 - mx);
      const float e2 = (lane < 32) ? __expf(m2 - mx) : 0.f;
      float sm = e1 + e2;
#pragma unroll
      for (int o = 32; o > 0; o >>= 1) sm += __shfl_xor(sm, o, 64);
      const float inv = 1.f / sm;
      P[r][lane] += e1 * inv;
      if (lane < 32) P[r][lane + 64] += e2 * inv;
    }
    __syncthreads();
  }

  uint16_t* Ob = encRb + (size_t)b * SS * DD;
  for (int e = t; e < SS * DD / 4; e += 256) {
    const int s = (e * 4) / DD;
    const int d = (e * 4) % DD;
    float4 v = ((const float4*)Eb)[e];
#pragma unroll
    for (int r = 0; r < RSEQ; ++r) {
      const float p = P[r][s];
      v.x += p * As[r][d + 0];
      v.y += p * As[r][d + 1];
      v.z += p * As[r][d + 2];
      v.w += p * As[r][d + 3];
    }
    uint2 w;
    w.x = pkrhu(v.x, v.y);
    w.y = pkrhu(v.z, v.w);
    *(uint2*)&Ob[e * 4] = w;
  }
}

// ---------------------------------------------------------------------------
// Kernel 2: projection GEMM, bf16 MFMA, classic LDS-staged (R1-proven shape).
// C[768, 4608] tiles 64m x 64n, BK=64, 4 waves 2x2 (wave tile 32x32).
// LDS rows padded to 80 bf16 -> even 8-round bank tiling on b128 ops.
// grid (12, 72) = 864 blocks (~3.4/CU hides the 2 barriers/chunk).
// Outputs: Hh f32 (bias folded), Ht bf16.
// ---------------------------------------------------------------------------
__global__ __launch_bounds__(256, 4) void k_proj(const uint16_t* __restrict__ Ab,
                                                 const uint16_t* __restrict__ Bt,
                                                 const float* __restrict__ pb,
                                                 float* __restrict__ Hh,
                                                 uint16_t* __restrict__ Htb) {
  const int m0 = blockIdx.x * 64;
  const int gn0 = blockIdx.y * 64;
  const bool isH = gn0 < D3;               // uniform per block
  const int n0 = isH ? gn0 : gn0 - D3;
  const int halfk = isH ? 0 : DD;
  const int t = threadIdx.x, w = t >> 6, lane = t & 63;
  const int wm = w >> 1, wn = w & 1;
  const int lm = lane & 15, q = lane >> 4;

  __shared__ uint16_t As[64][80];  // 10 KB each, row stride 160B
  __shared__ uint16_t Bs[64][80];

  const int srow = t >> 3;        // 0..31 (+32 on 2nd pass)
  const int sq8 = (t & 7) * 8;    // k-octet within chunk

  f32x4 acc[2][2];
#pragma unroll
  for (int a = 0; a < 2; ++a)
#pragma unroll
    for (int c = 0; c < 2; ++c) acc[a][c] = (f32x4){0.f, 0.f, 0.f, 0.f};

  const uint16_t* aSrc = Ab + (size_t)(m0 + srow) * DD + sq8;
  const uint16_t* bSrc = Bt + (size_t)(n0 + srow) * (2 * DD) + halfk + sq8;

  for (int k0 = 0; k0 < DD; k0 += 64) {
    const uint4 a0 = *(const uint4*)(aSrc + k0);
    const uint4 a1 = *(const uint4*)(aSrc + 32 * DD + k0);
    const uint4 b0 = *(const uint4*)(bSrc + k0);
    const uint4 b1 = *(const uint4*)(bSrc + 32 * (2 * DD) + k0);
    __syncthreads();  // previous chunk's frag reads complete
    *(uint4*)&As[srow][sq8] = a0;
    *(uint4*)&As[srow + 32][sq8] = a1;
    *(uint4*)&Bs[srow][sq8] = b0;
    *(uint4*)&Bs[srow + 32][sq8] = b1;
    __syncthreads();
#pragma unroll
    for (int kk = 0; kk < 2; ++kk) {
      bf16x8 af[2], bf[2];
#pragma unroll
      for (int mt = 0; mt < 2; ++mt)
        af[mt] = *(const bf16x8*)&As[wm * 32 + mt * 16 + lm][kk * 32 + q * 8];
#pragma unroll
      for (int nt = 0; nt < 2; ++nt)
        bf[nt] = *(const bf16x8*)&Bs[wn * 32 + nt * 16 + lm][kk * 32 + q * 8];
#pragma unroll
      for (int nt = 0; nt < 2; ++nt)
#pragma unroll
        for (int mt = 0; mt < 2; ++mt)
          acc[mt][nt] = __builtin_amdgcn_mfma_f32_16x16x32_bf16(af[mt], bf[nt], acc[mt][nt], 0, 0, 0);
    }
  }

  // epilogue: C layout col=lm, row=q*4+r
#pragma unroll
  for (int nt = 0; nt < 2; ++nt) {
    const int ncol = n0 + wn * 32 + nt * 16 + lm;
    const int mrow = m0 + wm * 32 + q * 4;
    if (isH) {
      const float bias = pb[ncol];
#pragma unroll
      for (int mt = 0; mt < 2; ++mt)
#pragma unroll
        for (int r = 0; r < 4; ++r)
          Hh[(size_t)(mrow + mt * 16 + r) * D3 + ncol] = acc[mt][nt][r] + bias;
    } else {
#pragma unroll
      for (int mt = 0; mt < 2; ++mt)
#pragma unroll
        for (int r = 0; r < 4; ++r)
          Htb[(size_t)(mrow + mt * 16 + r) * D3 + ncol] = bf16c(acc[mt][nt][r]);
    }
  }
}

// ---------------------------------------------------------------------------
// Kernel 3: pairwise GEMM. Grid = 256 blocks (1/CU): block = (b, 3 i's).
// 6 waves; wave w owns j-tile [16w,16w+16) x ALL 5 n-tiles x 3 i's.
// Per 32-k chunk per lane: 1 Ht uint4 (shared across 3 i-builds) + 5 Wb
// bf16x8 (identical across waves -> L1) all 1-deep prefetched; 6 broadcast
// ds_reads; 3 A-builds (28 VALU each, v_perm pack); 15 MFMA.
// One barrier total. acc = 60 VGPR; launch_bounds(384,2) -> no reg squeeze.
// ---------------------------------------------------------------------------
__global__ __launch_bounds__(384, 2) void k_pairs(const float* __restrict__ Hh,
                                                  const uint16_t* __restrict__ Htb,
                                                  const uint16_t* __restrict__ Wb,
                                                  const float* __restrict__ relb,
                                                  float* __restrict__ out) {
  const int blk = blockIdx.x;
  const int b = blk >> 5;             // /32
  const int i0 = (blk & 31) * 3;      // 3 consecutive i
  const int t = threadIdx.x;
  const int w = t >> 6, lane = t & 63;
  const int lm = lane & 15, q = lane >> 4;

  __shared__ float Hrow[3 * D3];  // 27.6 KB, rows contiguous

  // stage Hh rows i0..i0+2 (contiguous 27.6 KB block), coalesced float4
  const float* hh = Hh + ((size_t)b * SS + i0) * D3;
  for (int e = t; e < 3 * D3 / 4; e += 384) ((float4*)Hrow)[e] = ((const float4*)hh)[e];
  __syncthreads();  // the only barrier

  const uint16_t* htrow = Htb + ((size_t)b * SS + w * 16 + lm) * D3 + q * 8;
  const uint16_t* wbp = Wb + (size_t)lm * D3 + q * 8;

  f32x4 acc[3][5];
#pragma unroll
  for (int il = 0; il < 3; ++il)
#pragma unroll
    for (int nt = 0; nt < 5; ++nt) acc[il][nt] = (f32x4){0.f, 0.f, 0.f, 0.f};

  uint4 htc = *(const uint4*)htrow;
  bf16x8 bc[5];
#pragma unroll
  for (int nt = 0; nt < 5; ++nt) bc[nt] = *(const bf16x8*)(wbp + (size_t)nt * 16 * D3);

  for (int k0 = 0; k0 < D3; k0 += 32) {
    const int kn = (k0 + 32 < D3) ? k0 + 32 : 0;  // last iter: harmless reload
    const uint4 htn = *(const uint4*)(htrow + kn);
    bf16x8 bn[5];
#pragma unroll
    for (int nt = 0; nt < 5; ++nt) bn[nt] = *(const bf16x8*)(wbp + (size_t)nt * 16 * D3 + kn);

#pragma unroll
    for (int il = 0; il < 3; ++il) {
      const float4 hr0 = *(const float4*)&Hrow[il * D3 + k0 + q * 8];  // broadcast
      const float4 hr1 = *(const float4*)&Hrow[il * D3 + k0 + q * 8 + 4];
      union { bf16x8 v; uint32_t u[4]; } pk;
      pk.u[0] = pkrhu(fmaxf(lo16f(htc.x) + hr0.x, 0.f), fmaxf(hi16f(htc.x) + hr0.y, 0.f));
      pk.u[1] = pkrhu(fmaxf(lo16f(htc.y) + hr0.z, 0.f), fmaxf(hi16f(htc.y) + hr0.w, 0.f));
      pk.u[2] = pkrhu(fmaxf(lo16f(htc.z) + hr1.x, 0.f), fmaxf(hi16f(htc.z) + hr1.y, 0.f));
      pk.u[3] = pkrhu(fmaxf(lo16f(htc.w) + hr1.z, 0.f), fmaxf(hi16f(htc.w) + hr1.w, 0.f));
#pragma unroll
      for (int nt = 0; nt < 5; ++nt)
        acc[il][nt] = __builtin_amdgcn_mfma_f32_16x16x32_bf16(pk.v, bc[nt], acc[il][nt], 0, 0, 0);
    }
    htc = htn;
#pragma unroll
    for (int nt = 0; nt < 5; ++nt) bc[nt] = bn[nt];
  }

  // epilogue: C layout col=lm (c), row=q*4+r (j within tile)
#pragma unroll
  for (int nt = 0; nt < 5; ++nt) {
    const int c = nt * 16 + lm;
    if (c < NC) {
      const float rb = relb[c];
      const int r = c / 3, tg = c % 3;
#pragma unroll
      for (int il = 0; il < 3; ++il) {
        float* base = out + ((((size_t)b * TAG + tg) * RR + r) * SS + (i0 + il)) * SS + w * 16 + q * 4;
        float4 o;
        o.x = acc[il][nt][0] + rb;
        o.y = acc[il][nt][1] + rb;
        o.z = acc[il][nt][2] + rb;
        o.w = acc[il][nt][3] + rb;
        *(float4*)base = o;
      }
    }
  }
}

// ---------------------------------------------------------------------------
extern "C" void kernel_launch(void* const* d_in, const int* in_sizes, int n_in,
                              void* d_out, int out_size, void* d_ws, size_t ws_size,
                              hipStream_t stream) {
  const float* enc   = (const float*)d_in[0];  // [8,96,768]
  const float* rel   = (const float*)d_in[1];  // [24,8,768]
  const float* projW = (const float*)d_in[2];  // [1536,2304]
  const float* projb = (const float*)d_in[3];  // [2304]
  const float* relW  = (const float*)d_in[4];  // [2304,72]
  const float* relb  = (const float*)d_in[5];  // [72]
  float* out = (float*)d_out;                  // [8,3,24,96,96]

  float* Hh = (float*)d_ws;                               // 768*2304 f32
  uint16_t* Htb = (uint16_t*)(Hh + (size_t)DD * D3);      // 768*2304 bf16
  uint16_t* Wb = Htb + (size_t)DD * D3;                   // 96*2304 bf16
  uint16_t* Tp = Wb + (size_t)96 * D3;                    // 2304*1536 bf16
  uint16_t* Ab = Tp + (size_t)D3 * 2 * DD;                // 768*768 bf16

  k_prepW<<<(96 * D3) / 256, 256, 0, stream>>>(relW, Wb);
  k_trans<<<dim3(36, 24), 256, 0, stream>>>(projW, Tp);
  k_refine<<<BB, 256, 0, stream>>>(enc, rel, Ab);
  k_proj<<<dim3(12, 72), 256, 0, stream>>>(Ab, Tp, projb, Hh, Htb);
  k_pairs<<<256, 384, 0, stream>>>(Hh, Htb, Wb, relb, out);
}